// Round 7
// baseline (225.886 us; speedup 1.0000x reference)
//
#include <hip/hip_runtime.h>
#include <stdint.h>

typedef unsigned long long u64;
typedef float v2 __attribute__((ext_vector_type(2)));

#define THRESH_F 5e-5f
#define BB 128
#define HH 384
#define WW_ 384
#define WPR 6                        // u64 words per 384-pixel row
#define IMG_WORDS (HH*WPR)           // 2304
#define OH 378
#define OW 378
#define PIX (BB*HH*WW_)              // 18874368
#define COVN (49.0f/48.0f)

#define SLAB 48                      // output rows per morph block
#define HALO 30                      // morphology chain depth: 1 + 15 + 14
#define MAXROWS (SLAB + 2*HALO)      // 108
#define MAXW (MAXROWS * WPR)         // 648

#define BIN_BLOCKS 1536

// div by 6 via magic, valid for w < 131072
__device__ __forceinline__ int div6(int w) { return (w * 43691) >> 18; }

// ---- K1: binarize Y -> bits. Each wave: 256 contiguous elems per step -----
__global__ void __launch_bounds__(256) k_binarize(const float* __restrict__ Y,
                                                  u64* __restrict__ bits,
                                                  float* __restrict__ accum) {
    if (blockIdx.x == 0) {           // zero accum slots (consumed by k_ssim later)
        for (int i = threadIdx.x; i < 1024; i += 256) accum[i] = 0.f;
    }
    const int lane = threadIdx.x & 63;
    const int wave = (blockIdx.x * 256 + threadIdx.x) >> 6;   // global wave id
    const int nwaves = BIN_BLOCKS * 4;
    const int NSTEP = PIX / 256;                              // 73728
    for (int s = wave; s < NSTEP; s += nwaves) {
        size_t base = (size_t)s * 256 + lane;
        float a0 = Y[base];
        float a1 = Y[base + 64];
        float a2 = Y[base + 128];
        float a3 = Y[base + 192];
        u64 b0 = __ballot(a0 > THRESH_F);
        u64 b1 = __ballot(a1 > THRESH_F);
        u64 b2 = __ballot(a2 > THRESH_F);
        u64 b3 = __ballot(a3 > THRESH_F);
        if (lane < 4) {
            u64 v = (lane == 0) ? b0 : (lane == 1) ? b1 : (lane == 2) ? b2 : b3;
            bits[(size_t)s * 4 + lane] = v;
        }
    }
}

// ---- K2: fused morphology on bits, 8 slabs per image (1024 blocks) --------
__global__ void __launch_bounds__(256) k_morph(const u64* __restrict__ gbits,
                                               u64* __restrict__ gout_all) {
    __shared__ u64 A[MAXW];
    __shared__ u64 Bf[MAXW];
    const int blk = blockIdx.x;
    const int b = blk >> 3;
    const int slab = blk & 7;
    const int r0 = slab * SLAB;
    const int w0row = (r0 - HALO < 0) ? 0 : r0 - HALO;
    int w1row = r0 + SLAB + HALO; if (w1row > HH) w1row = HH;
    const int nrows = w1row - w0row;                  // 78 or 108
    const int NW = nrows * WPR;
    const int t = threadIdx.x;

    const u64* gin = gbits + (size_t)b * IMG_WORDS + (size_t)w0row * WPR;
    for (int w = t; w < NW; w += 256) A[w] = gin[w];
    __syncthreads();

    // ---- erode3: A -> Bf ----
    for (int w = t; w < NW; w += 256) {
        int row = div6(w);
        int ww = w - row * 6;
        int rlo = row > 0 ? row - 1 : row;
        int rhi = row < nrows - 1 ? row + 1 : row;
        u64 res = ~0ull;
        for (int rr = rlo; rr <= rhi; ++rr) {
            const u64* rp = &A[rr * 6];
            u64 a = ww > 0 ? rp[ww - 1] : 0ull;
            u64 bb = rp[ww];
            u64 c = ww < 5 ? rp[ww + 1] : 0ull;
            u64 l  = (bb << 1) | (ww > 0 ? (a >> 63) : 1ull);
            u64 r2 = (bb >> 1) | (ww < 5 ? (c << 63) : (1ull << 63));
            res &= bb & l & r2;
        }
        Bf[w] = res;
    }
    __syncthreads();

    // ---- dilate_h15: Bf -> A ----
    for (int w = t; w < NW; w += 256) {
        int row = div6(w);
        int ww = w - row * 6;
        const u64* rp = &Bf[row * 6];
        u64 a = ww > 0 ? rp[ww - 1] : 0ull;
        u64 bb = rp[ww];
        u64 c = ww < 5 ? rp[ww + 1] : 0ull;
        __uint128_t X = (((__uint128_t)bb) << 64) | a;
        X |= X << 1; X |= X << 2; X |= X << 4; X |= X << 8;
        __uint128_t Z = (((__uint128_t)c) << 64) | bb;
        Z |= Z >> 1; Z |= Z >> 2; Z |= Z >> 4; Z |= Z >> 8;
        A[w] = (u64)(X >> 64) | (u64)Z;
    }
    __syncthreads();

    // ---- dilate_v15: A -> Bf ----
    for (int w = t; w < NW; w += 256) {
        int row = div6(w);
        int ww = w - row * 6;
        int lo2 = row - 15 < 0 ? 0 : row - 15;
        int hi2 = row + 15 > nrows - 1 ? nrows - 1 : row + 15;
        u64 acc = 0ull;
        for (int rr = lo2; rr <= hi2; ++rr) acc |= A[rr * 6 + ww];
        Bf[w] = acc;
    }
    __syncthreads();

    // ---- erode_h14: Bf -> A ----
    for (int w = t; w < NW; w += 256) {
        int row = div6(w);
        int ww = w - row * 6;
        const u64* rp = &Bf[row * 6];
        u64 a = ww > 0 ? rp[ww - 1] : ~0ull;
        u64 bb = rp[ww];
        u64 c = ww < 5 ? rp[ww + 1] : ~0ull;
        u64 na = ~a, nb = ~bb, nc = ~c;
        __uint128_t X = (((__uint128_t)nb) << 64) | na;
        X |= X << 1; X |= X << 2; X |= X << 4; X |= X << 7;
        __uint128_t Z = (((__uint128_t)nc) << 64) | nb;
        Z |= Z >> 1; Z |= Z >> 2; Z |= Z >> 4; Z |= Z >> 7;
        A[w] = ~((u64)(X >> 64) | (u64)Z);
    }
    __syncthreads();

    // ---- erode_v14: A -> global, output rows [r0, r0+48) ----
    u64* gout = gout_all + (size_t)b * IMG_WORDS;
    const int base = r0 - w0row;
    for (int w = t; w < SLAB * WPR; w += 256) {
        int lrow = div6(w);
        int ww = w - lrow * 6;
        int lr = base + lrow;
        int lo2 = lr - 14 < 0 ? 0 : lr - 14;
        int hi2 = lr + 14 > nrows - 1 ? nrows - 1 : lr + 14;
        u64 acc = ~0ull;
        for (int rr = lo2; rr <= hi2; ++rr) acc &= A[rr * 6 + ww];
        gout[(size_t)(r0 + lrow) * WPR + ww] = acc;
    }
}

// ---- K3: masked SSIM, lane-cooperative: each lane loads ONE pixel pair ----
// Wave covers 61 output pairs + 3 halo lanes. Horizontal 7-sums assembled
// from neighbor pair-sums via shuffles:
//   h(2g)   = S[l] + S[l+1] + S[l+2] + E[l+3]      (E = even-pixel value)
//   h(2g+1) = odd[l] + S[l+1] + S[l+2] + S[l+3]
// Loads/row: 1 v2 X + 1 v2 Y + 1 mask dword (vs 10 before); products 6 (vs 24).
// grid (4, 7, 128), block 128 (2 chunk-waves). Depth-2 row prefetch.
__global__ void __launch_bounds__(128) k_ssim(
    const float* __restrict__ Xg, const float* __restrict__ Yg,
    const float* __restrict__ drg, const u64* __restrict__ Mg,
    float* __restrict__ accum)
{
    const int lane = threadIdx.x & 63;
    const int cz = threadIdx.x >> 6;                  // 0..1
    const int span = blockIdx.x;                      // 0..3
    const int chunk = blockIdx.y * 2 + cz;            // 0..13
    const int b  = blockIdx.z;

    const int gRaw = span * 61 + lane;                // load-pair index
    const int g = (gRaw > 191) ? 191 : gRaw;          // clamp loads in-bounds
    const bool valid = (lane < 61) && (gRaw < 189);
    const int i0 = chunk * 27;                        // 378 = 14*27 exact

    const float drv = drg[b];
    const float C1q = 1e-4f * drv * drv * 2401.0f;    // C1*49^2
    const float C2q = 9e-4f * drv * drv * 2401.0f;    // C2*49^2

    const float* xp = Xg + ((size_t)b * HH + i0) * WW_ + 2 * g;
    const float* yp = Yg + ((size_t)b * HH + i0) * WW_ + 2 * g;
    const unsigned* mp = (const unsigned*)Mg + ((size_t)b * HH + i0) * 12 + (g >> 4);
    const int msh = (g & 15) * 2;

    const int l1 = (lane + 1) & 63;
    const int l2 = (lane + 2) & 63;
    const int l3 = (lane + 3) & 63;

    v2 r0[7], r1[7], r2[7], r3[7], r4[7];
    #pragma unroll
    for (int t = 0; t < 7; ++t) {
        r0[t] = 0.f; r1[t] = 0.f; r2[t] = 0.f; r3[t] = 0.f; r4[t] = 0.f;
    }
    v2 s0 = 0.f, s1 = 0.f, s2 = 0.f, s3 = 0.f, s4 = 0.f;
    float lsum = 0.0f;

    // pipeline: stage A = row rr, stage B = row rr+1
    v2 aX = *(const v2*)(xp);
    v2 aY = *(const v2*)(yp);
    unsigned aM = mp[0];
    v2 bX = *(const v2*)(xp + WW_);
    v2 bY = *(const v2*)(yp + WW_);
    unsigned bM = mp[12];

    for (int bs = 0; bs < 35; bs += 7) {
        #pragma unroll
        for (int ph = 0; ph < 7; ++ph) {
            const int rr = bs + ph;
            if (rr >= 33) break;                      // uniform

            // ---- prefetch row rr+2 ----
            v2 tX = 0.f, tY = 0.f;
            unsigned tM = 0u;
            if (rr + 2 < 33) {
                tX = *(const v2*)(xp + (size_t)(rr + 2) * WW_);
                tY = *(const v2*)(yp + (size_t)(rr + 2) * WW_);
                tM = mp[(rr + 2) * 12];
            }

            // ---- mask + products for own pair ----
            float m0 = (float)((aM >> msh) & 1u);
            float m1 = (float)((aM >> (msh + 1)) & 1u);
            float xe = aX.x * m0, xo = aX.y * m1;
            float ye = aY.x * m0, yo = aY.y * m1;
            float xxe = xe * xe, xxo = xo * xo;
            float yye = ye * ye, yyo = yo * yo;
            float xye = xe * ye, xyo = xo * yo;

            // pair sums
            float SX  = xe + xo,   SY  = ye + yo;
            float SXX = xxe + xxo, SYY = yye + yyo, SXY = xye + xyo;

            // neighbor shuffles (4 per quantity)
            float SX1 = __shfl(SX, l1),  SX2 = __shfl(SX, l2),  SX3 = __shfl(SX, l3),  EX = __shfl(xe, l3);
            float SY1 = __shfl(SY, l1),  SY2 = __shfl(SY, l2),  SY3 = __shfl(SY, l3),  EY = __shfl(ye, l3);
            float SA1 = __shfl(SXX, l1), SA2 = __shfl(SXX, l2), SA3 = __shfl(SXX, l3), EA = __shfl(xxe, l3);
            float SB1 = __shfl(SYY, l1), SB2 = __shfl(SYY, l2), SB3 = __shfl(SYY, l3), EB = __shfl(yye, l3);
            float SC1 = __shfl(SXY, l1), SC2 = __shfl(SXY, l2), SC3 = __shfl(SXY, l3), EC = __shfl(xye, l3);

            float TX = SX1 + SX2, TY = SY1 + SY2, TA = SA1 + SA2, TB = SB1 + SB2, TC = SC1 + SC2;
            v2 hX  = { (SX + EX) + TX,   (xo + TX) + SX3 };
            v2 hY  = { (SY + EY) + TY,   (yo + TY) + SY3 };
            v2 hXX = { (SXX + EA) + TA,  (xxo + TA) + SA3 };
            v2 hYY = { (SYY + EB) + TB,  (yyo + TB) + SB3 };
            v2 hXY = { (SXY + EC) + TC,  (xyo + TC) + SC3 };

            // vertical slide, static ring index
            v2 o;
            o = r0[ph]; r0[ph] = hX;  s0 += hX  - o;
            o = r1[ph]; r1[ph] = hY;  s1 += hY  - o;
            o = r2[ph]; r2[ph] = hXX; s2 += hXX - o;
            o = r3[ph]; r3[ph] = hYY; s3 += hYY - o;
            o = r4[ph]; r4[ph] = hXY; s4 += hXY - o;

            if (rr >= 6) {
                v2 t3  = s0 * s1;
                v2 t12 = s1 * s1 + s0 * s0;
                v2 A1  = 2.0f * t3 + C1q;
                v2 u   = 49.0f * s4 - t3;
                v2 A2  = (2.0f * COVN) * u + C2q;
                v2 B1  = t12 + C1q;
                v2 w   = s2 + s3;
                v2 vsum = 49.0f * w - t12;
                v2 B2  = COVN * vsum + C2q;
                v2 num = A1 * A2;
                v2 den = B1 * B2;
                float q0 = __builtin_amdgcn_rcpf(den.x);
                float q1 = __builtin_amdgcn_rcpf(den.y);
                float val = num.x * q0 + num.y * q1;
                lsum += valid ? val : 0.0f;
            }

            // ---- rotate pipeline (renamed by full unroll) ----
            aX = bX; aY = bY; aM = bM;
            bX = tX; bY = tY; bM = tM;
        }
    }

    // wave-level reduce (no LDS)
    #pragma unroll
    for (int off = 32; off > 0; off >>= 1) lsum += __shfl_down(lsum, off);
    if (lane == 0) {
        int flat = ((blockIdx.z * 14 + chunk) * 4 + span);
        atomicAdd(&accum[flat & 1023], lsum);
    }
}

// ---- K4: finalize -> 1 - sum/N (double accumulate) ------------------------
__global__ void k_final(const float* __restrict__ accum, float* __restrict__ out) {
    __shared__ double sm[256];
    double v = 0.0;
    for (int i = threadIdx.x; i < 1024; i += 256) v += (double)accum[i];
    sm[threadIdx.x] = v;
    __syncthreads();
    #pragma unroll
    for (int off = 128; off > 0; off >>= 1) {
        if (threadIdx.x < off) sm[threadIdx.x] += sm[threadIdx.x + off];
        __syncthreads();
    }
    if (threadIdx.x == 0) {
        out[0] = (float)(1.0 - sm[0] / 18289152.0);   // N = 128*378*378
    }
}

extern "C" void kernel_launch(void* const* d_in, const int* in_sizes, int n_in,
                              void* d_out, int out_size, void* d_ws, size_t ws_size,
                              hipStream_t stream) {
    const float* X  = (const float*)d_in[0];
    const float* Y  = (const float*)d_in[1];
    const float* dr = (const float*)d_in[2];
    float* out = (float*)d_out;

    char* ws = (char*)d_ws;
    float* accum = (float*)ws;                        // 4 KB
    u64* maskB = (u64*)(ws + 4096);                                  // 2.36 MB final mask
    u64* bitsRaw = (u64*)(ws + 4096 + (size_t)(BB * IMG_WORDS) * 8); // 2.36 MB binarized

    k_binarize<<<BIN_BLOCKS, 256, 0, stream>>>(Y, bitsRaw, accum);
    k_morph<<<BB * 8, 256, 0, stream>>>(bitsRaw, maskB);
    dim3 g(4, 7, 128);
    k_ssim<<<g, 128, 0, stream>>>(X, Y, dr, maskB, accum);
    k_final<<<1, 256, 0, stream>>>(accum, out);
}